// Round 11
// baseline (56.127 us; speedup 1.0000x reference)
//
#include <hip/hip_runtime.h>
#include <hip/hip_fp16.h>

#define NN 1536      // n_nodes
#define FDIM 32      // p == fts == 32
#define TG 96        // GEMM tile (grid 16x16x3 = 768 blocks = 3/CU)
#define KS 32        // K-step (one mfma_16x16x32 worth of K)
#define NSPLIT 3     // split-K factor
#define NTH 16       // K-tiles per split (1536/3/32)

typedef __attribute__((ext_vector_type(8))) __bf16 bf16x8;
typedef __attribute__((ext_vector_type(4))) float f32x4;
typedef _Float16 h16x2 __attribute__((ext_vector_type(2)));

typedef __attribute__((address_space(3))) unsigned char as3_u8;
typedef __attribute__((address_space(1))) unsigned char as1_u8;

__device__ __forceinline__ void gload_lds16(const void* g, void* l) {
    __builtin_amdgcn_global_load_lds((const as1_u8*)g, (as3_u8*)l, 16, 0, 0);
}

// ---------------------------------------------------------------------------
// Split A into bf16 hi/lo: Ah = rne_bf16(a), Al = rne_bf16(a - float(Ah)).
// ---------------------------------------------------------------------------
__device__ __forceinline__ unsigned short bf16rne(float f) {
    unsigned u = __float_as_uint(f);
    return (unsigned short)((u + 0x7FFFu + ((u >> 16) & 1u)) >> 16);
}

__global__ __launch_bounds__(256) void gud_split(const float* __restrict__ A,
                                                 unsigned short* __restrict__ Ah,
                                                 unsigned short* __restrict__ Al) {
    int gid = blockIdx.x * 256 + threadIdx.x;      // 4 floats per thread
    float4 v = reinterpret_cast<const float4*>(A)[gid];
    ushort4 h, l;
    float x;
    x = v.x; h.x = bf16rne(x); l.x = bf16rne(x - __uint_as_float((unsigned)h.x << 16));
    x = v.y; h.y = bf16rne(x); l.y = bf16rne(x - __uint_as_float((unsigned)h.y << 16));
    x = v.z; h.z = bf16rne(x); l.z = bf16rne(x - __uint_as_float((unsigned)h.z << 16));
    x = v.w; h.w = bf16rne(x); l.w = bf16rne(x - __uint_as_float((unsigned)h.w << 16));
    reinterpret_cast<ushort4*>(Ah)[gid] = h;
    reinterpret_cast<ushort4*>(Al)[gid] = l;
}

// ---------------------------------------------------------------------------
// Prep: Q_l = P @ W1[l] for l = 1,2.  f16 outputs:
// QIh[i][l*32+f] = f16(Q + b1),  RJh[j][l*32+f] = f16(-Q).
// ---------------------------------------------------------------------------
__global__ __launch_bounds__(256) void gud_prep(const float* __restrict__ P,
                                                const float* __restrict__ W1,
                                                const float* __restrict__ b1,
                                                _Float16* __restrict__ QIh,
                                                _Float16* __restrict__ RJh) {
    int gid = blockIdx.x * 256 + threadIdx.x;   // 0 .. NN*64-1
    int i  = gid >> 6;
    int lf = gid & 63;
    int l  = (lf >> 5) + 1;   // 1 or 2
    int f  = lf & 31;
    const float* prow = P + i * FDIM;
    const float* w    = W1 + l * FDIM * FDIM + f;
    float q = 0.f;
#pragma unroll
    for (int c = 0; c < FDIM; ++c) q = fmaf(prow[c], w[c * FDIM], q);
    QIh[i * 64 + lf] = (_Float16)(q + b1[l * FDIM + f]);
    RJh[i * 64 + lf] = (_Float16)(-q);
}

// ---------------------------------------------------------------------------
// Split-K(x3) MFMA GEMM: blockIdx.z = K-third. acc = A*A over this third via
// bf16 hi/lo (AhBh + AlBh + AhBl). Each third writes its OWN partial buffer
// (plain coalesced stores; atomics caused cross-XCD line ping-pong in r9).
// 2 LDS buffers (49KB) -> 3 blocks/CU co-resident: their independent
// schedules fill each other's vmcnt/barrier drain bubbles (m114 mechanism).
// ---------------------------------------------------------------------------
__global__ __launch_bounds__(256, 3) void gud_gemm(
        const unsigned short* __restrict__ Ah,
        const unsigned short* __restrict__ Al,
        float* __restrict__ Pk) {
    __shared__ char smem[2 * 24576];   // 49152 B -> 3 blocks/CU

    const int tid  = threadIdx.x;
    const int lane = tid & 63;
    const int w    = tid >> 6;          // wave 0..3
    const int wr   = w >> 1, wc = w & 1;
    const int i0   = blockIdx.y * TG;
    const int j0   = blockIdx.x * TG;
    const int kh   = blockIdx.z;        // K-third 0/1/2
    const int kbase = kh * (NN / NSPLIT) * 2;   // byte offset of this third

    // ---- staging: wave w owns subtile w (0=Ah@i0, 1=Al@i0, 2=Ah@j0, 3=Al@j0)
    const unsigned short* src = (w & 1) ? Al : Ah;
    const int rowbase = (w < 2) ? i0 : j0;
    int goffs[6];
#pragma unroll
    for (int s = 0; s < 6; ++s) {
        int rt    = 16 * s + (lane >> 2);          // row within tile 0..95
        int chunk = (lane & 3) ^ ((rt >> 1) & 3);  // inverse swizzle on source
        goffs[s]  = (rowbase + rt) * (NN * 2) + kbase + chunk * 16;
    }

    // ---- fragment read offsets (swizzled); rows of 64B = K=32 bf16
    int aoff[3], boff[3];
    const int kb = lane >> 4;
#pragma unroll
    for (int m = 0; m < 3; ++m) {
        int ra  = wr * 48 + m * 16 + (lane & 15);
        aoff[m] = ra * 64 + ((kb ^ ((ra >> 1) & 3)) * 16);
        int rb  = wc * 48 + m * 16 + (lane & 15);
        boff[m] = rb * 64 + ((kb ^ ((rb >> 1) & 3)) * 16);
    }

    f32x4 acc[3][3];
#pragma unroll
    for (int m = 0; m < 3; ++m)
#pragma unroll
        for (int n = 0; n < 3; ++n) acc[m][n] = (f32x4){0.f, 0.f, 0.f, 0.f};

    auto compute = [&](const char* buf) {
        bf16x8 ahf[3], alf[3], bhf[3], blf[3];
#pragma unroll
        for (int m = 0; m < 3; ++m) {
            ahf[m] = *(const bf16x8*)(buf + 0     + aoff[m]);
            alf[m] = *(const bf16x8*)(buf + 6144  + aoff[m]);
            bhf[m] = *(const bf16x8*)(buf + 12288 + boff[m]);
            blf[m] = *(const bf16x8*)(buf + 18432 + boff[m]);
        }
#pragma unroll
        for (int m = 0; m < 3; ++m)
#pragma unroll
            for (int n = 0; n < 3; ++n) {
                acc[m][n] = __builtin_amdgcn_mfma_f32_16x16x32_bf16(ahf[m], bhf[n], acc[m][n], 0, 0, 0);
                acc[m][n] = __builtin_amdgcn_mfma_f32_16x16x32_bf16(alf[m], bhf[n], acc[m][n], 0, 0, 0);
                acc[m][n] = __builtin_amdgcn_mfma_f32_16x16x32_bf16(ahf[m], blf[n], acc[m][n], 0, 0, 0);
            }
    };

    // ---- prologue: stage k-tile 0 into buffer 0, drain, barrier
#pragma unroll
    for (int s = 0; s < 6; ++s)
        gload_lds16((const char*)src + goffs[s], smem + w * 6144 + s * 1024);
    asm volatile("s_waitcnt vmcnt(0)" ::: "memory");
    __builtin_amdgcn_s_barrier();

    // ---- main loop: STAGE(kt+1 -> buf^1) || compute(buf); vmcnt(0)+barrier.
    // Drain bubble is filled by the 2 other co-resident blocks on this CU.
    int cur = 0;
    for (int kt = 0; kt < NTH; ++kt) {
        if (kt + 1 < NTH) {
            char* dst = smem + (cur ^ 1) * 24576 + w * 6144;
            const int kbyte = (kt + 1) * (KS * 2);
#pragma unroll
            for (int s = 0; s < 6; ++s)
                gload_lds16((const char*)src + goffs[s] + kbyte, dst + s * 1024);
        }
        compute(smem + cur * 24576);
        asm volatile("s_waitcnt vmcnt(0)" ::: "memory");
        __builtin_amdgcn_s_barrier();
        cur ^= 1;
    }

    // ---- epilogue: plain coalesced stores to this third's partial buffer
    float* dst = Pk + (size_t)kh * NN * NN;
    const int crow = (lane >> 4) * 4;
    const int ccol = lane & 15;
#pragma unroll
    for (int m = 0; m < 3; ++m)
#pragma unroll
        for (int n = 0; n < 3; ++n) {
            const int ib = i0 + wr * 48 + m * 16 + crow;
            const int jb = j0 + wc * 48 + n * 16 + ccol;
#pragma unroll
            for (int r = 0; r < 4; ++r)
                dst[(size_t)(ib + r) * NN + jb] = acc[m][n][r];
        }
}

// ---------------------------------------------------------------------------
// Conv pass: out[i,j] = A[i,j]*(m1+bb1) + (P0+P1+P2)[i,j]*(m2+bb2) + diag c0
// 1152 blocks: 8 i-rows (QI tile in LDS, broadcast reads) x 256 j (RJ in
// registers). f16 packed math: pk_add + pk_max + v_dot2_f32_f16.
// ---------------------------------------------------------------------------
__global__ __launch_bounds__(256) void gud_conv(
        const float* __restrict__ A,
        const float* __restrict__ Pk,
        const _Float16* __restrict__ QIh,
        const _Float16* __restrict__ RJh,
        const float* __restrict__ b1,
        const float* __restrict__ W2,
        const float* __restrict__ b2,
        float* __restrict__ out) {
    __shared__ uint4 QIs[64];          // 8 rows x 128 B

    const int tid = threadIdx.x;
    const int j   = blockIdx.x * 256 + tid;
    const int i0  = blockIdx.y * 8;

    if (tid < 64) {
        int row = tid >> 3, c = tid & 7;
        QIs[tid] = ((const uint4*)(QIh + (size_t)(i0 + row) * 64))[c];
    }

    uint4 rj4[8];
#pragma unroll
    for (int c = 0; c < 8; ++c)
        rj4[c] = ((const uint4*)(RJh + (size_t)j * 64))[c];
    const unsigned* rw = (const unsigned*)rj4;

    // W2 layers 1,2 concat (feature f -> W2[32+f]) as f16 pairs
    h16x2 w2h[32];
#pragma unroll
    for (int k = 0; k < 32; ++k) {
        h16x2 t; t.x = (_Float16)W2[32 + 2 * k]; t.y = (_Float16)W2[33 + 2 * k];
        w2h[k] = t;
    }
    float c0 = b2[0];
#pragma unroll
    for (int f = 0; f < FDIM; ++f) c0 = fmaf(fmaxf(b1[f], 0.f), W2[f], c0);
    const float bb1 = b2[1], bb2 = b2[2];
    const h16x2 z = {(_Float16)0, (_Float16)0};

    const float* P0 = Pk;
    const float* P1 = Pk + (size_t)NN * NN;
    const float* P2 = Pk + 2 * (size_t)NN * NN;

    __syncthreads();

#pragma unroll
    for (int ii = 0; ii < 8; ++ii) {
        uint4 q4[8];
#pragma unroll
        for (int c = 0; c < 8; ++c) q4[c] = QIs[ii * 8 + c];
        const unsigned* qw = (const unsigned*)q4;

        float m1 = 0.f, m2 = 0.f;
#pragma unroll
        for (int k = 0; k < 16; ++k) {
            h16x2 h = __builtin_bit_cast(h16x2, qw[k]) + __builtin_bit_cast(h16x2, rw[k]);
            h = __builtin_elementwise_max(h, z);
            m1 = __builtin_amdgcn_fdot2(h, w2h[k], m1, false);
        }
#pragma unroll
        for (int k = 16; k < 32; ++k) {
            h16x2 h = __builtin_bit_cast(h16x2, qw[k]) + __builtin_bit_cast(h16x2, rw[k]);
            h = __builtin_elementwise_max(h, z);
            m2 = __builtin_amdgcn_fdot2(h, w2h[k], m2, false);
        }

        const size_t off = (size_t)(i0 + ii) * NN + j;
        float a2 = (P0[off] + P1[off]) + P2[off];
        float v = A[off] * (m1 + bb1) + a2 * (m2 + bb2);
        if (i0 + ii == j) v += c0;
        out[off] = v;
    }
}

// ---------------------------------------------------------------------------
extern "C" void kernel_launch(void* const* d_in, const int* in_sizes, int n_in,
                              void* d_out, int out_size, void* d_ws, size_t ws_size,
                              hipStream_t stream) {
    const float* A  = (const float*)d_in[0];   // [NN,NN] A_norm (symmetric)
    const float* P  = (const float*)d_in[1];   // [NN,32]
    const float* W1 = (const float*)d_in[2];   // [3,32,32]
    const float* b1 = (const float*)d_in[3];   // [3,32]
    const float* W2 = (const float*)d_in[4];   // [3,32,1]
    const float* b2 = (const float*)d_in[5];   // [3,1]
    float* out = (float*)d_out;

    float* Pk = (float*)d_ws;                                    // 3 x NN*NN f32
    unsigned short* Ahh = (unsigned short*)(Pk + 3 * (size_t)NN * NN);  // NN*NN bf16
    unsigned short* All = Ahh + (size_t)NN * NN;                 // NN*NN bf16
    _Float16* QIh = (_Float16*)(All + (size_t)NN * NN);          // NN*64 f16
    _Float16* RJh = QIh + (size_t)NN * 64;                       // NN*64 f16

    gud_split<<<dim3(NN * NN / 1024), 256, 0, stream>>>(A, Ahh, All);
    gud_prep<<<dim3(NN * 64 / 256), 256, 0, stream>>>(P, W1, b1, QIh, RJh);
    gud_gemm<<<dim3(NN / TG, NN / TG, NSPLIT), 256, 0, stream>>>(Ahh, All, Pk);
    gud_conv<<<dim3(NN / 256, NN / 8), 256, 0, stream>>>(A, Pk, QIh, RJh,
                                                         b1, W2, b2, out);
}

// Round 12
// 53.388 us; speedup vs baseline: 1.0513x; 1.0513x over previous
//
#include <hip/hip_runtime.h>
#include <hip/hip_fp16.h>

#define NN 1536      // n_nodes
#define FDIM 32      // p == fts == 32
#define TG 192       // GEMM tile (grid 8x8x4 = 256 blocks = 1/CU)
#define KS 32        // K-step (64 B LDS row)
#define NSPLIT 4     // split-K factor
#define NTH 12       // K-tiles per split (1536/4/32)

typedef __attribute__((ext_vector_type(8))) __bf16 bf16x8;
typedef __attribute__((ext_vector_type(16))) float f32x16;
typedef _Float16 h16x2 __attribute__((ext_vector_type(2)));

typedef __attribute__((address_space(3))) unsigned char as3_u8;
typedef __attribute__((address_space(1))) unsigned char as1_u8;

__device__ __forceinline__ void gload_lds16(const void* g, void* l) {
    __builtin_amdgcn_global_load_lds((const as1_u8*)g, (as3_u8*)l, 16, 0, 0);
}

// ---------------------------------------------------------------------------
// Split A into bf16 hi/lo: Ah = rne_bf16(a), Al = rne_bf16(a - float(Ah)).
// ---------------------------------------------------------------------------
__device__ __forceinline__ unsigned short bf16rne(float f) {
    unsigned u = __float_as_uint(f);
    return (unsigned short)((u + 0x7FFFu + ((u >> 16) & 1u)) >> 16);
}

__global__ __launch_bounds__(256) void gud_split(const float* __restrict__ A,
                                                 unsigned short* __restrict__ Ah,
                                                 unsigned short* __restrict__ Al) {
    int gid = blockIdx.x * 256 + threadIdx.x;      // 4 floats per thread
    float4 v = reinterpret_cast<const float4*>(A)[gid];
    ushort4 h, l;
    float x;
    x = v.x; h.x = bf16rne(x); l.x = bf16rne(x - __uint_as_float((unsigned)h.x << 16));
    x = v.y; h.y = bf16rne(x); l.y = bf16rne(x - __uint_as_float((unsigned)h.y << 16));
    x = v.z; h.z = bf16rne(x); l.z = bf16rne(x - __uint_as_float((unsigned)h.z << 16));
    x = v.w; h.w = bf16rne(x); l.w = bf16rne(x - __uint_as_float((unsigned)h.w << 16));
    reinterpret_cast<ushort4*>(Ah)[gid] = h;
    reinterpret_cast<ushort4*>(Al)[gid] = l;
}

// ---------------------------------------------------------------------------
// Prep: Q_l = P @ W1[l] for l = 1,2.  f16 outputs:
// QIh[i][l*32+f] = f16(Q + b1),  RJh[j][l*32+f] = f16(-Q).
// ---------------------------------------------------------------------------
__global__ __launch_bounds__(256) void gud_prep(const float* __restrict__ P,
                                                const float* __restrict__ W1,
                                                const float* __restrict__ b1,
                                                _Float16* __restrict__ QIh,
                                                _Float16* __restrict__ RJh) {
    int gid = blockIdx.x * 256 + threadIdx.x;   // 0 .. NN*64-1
    int i  = gid >> 6;
    int lf = gid & 63;
    int l  = (lf >> 5) + 1;   // 1 or 2
    int f  = lf & 31;
    const float* prow = P + i * FDIM;
    const float* w    = W1 + l * FDIM * FDIM + f;
    float q = 0.f;
#pragma unroll
    for (int c = 0; c < FDIM; ++c) q = fmaf(prow[c], w[c * FDIM], q);
    QIh[i * 64 + lf] = (_Float16)(q + b1[l * FDIM + f]);
    RJh[i * 64 + lf] = (_Float16)(-q);
}

// ---------------------------------------------------------------------------
// Split-K(x4) MFMA GEMM, TG=192, 32x32x16 frags. acc = A*A over this K-quarter
// via bf16 hi/lo (AhBh + AlBh + AhBl, one f32x16 acc per frag). Per K-step the
// block issues 216 MFMA (1743 cyc/SIMD) vs ~1150 cyc LDS -> MFMA-bound; the
// per-iter barrier/vmcnt overhead that dominated TG=96 is now ~10%.
// 3 LDS buffers (147456 B), 2-deep prefetch, counted vmcnt(12).
// Each split writes its own partial (plain stores; atomics ping-pong r9).
// ---------------------------------------------------------------------------
__global__ __launch_bounds__(256, 1) void gud_gemm(
        const unsigned short* __restrict__ Ah,
        const unsigned short* __restrict__ Al,
        float* __restrict__ Pk) {
    __shared__ char smem[3 * 49152];   // 147456 B

    const int tid  = threadIdx.x;
    const int lane = tid & 63;
    const int w    = tid >> 6;          // wave 0..3
    const int wr   = w >> 1, wc = w & 1;

    // XCD-chunked swizzle over the 256-block 1-D grid (256 % 8 == 0):
    // XCD k owns 32 consecutive swz = 4 i-panels x 8 j-panels of one split.
    const int lin = blockIdx.x;
    const int swz = (lin & 7) * 32 + (lin >> 3);
    const int kh  = swz >> 6;           // split 0..3
    const int by  = (swz >> 3) & 7;
    const int bx  = swz & 7;
    const int i0  = by * TG;
    const int j0  = bx * TG;
    const int kbase = kh * (NN / NSPLIT) * 2;   // byte offset of this quarter

    // ---- staging: wave w owns subtile w (0=Ah@i0, 1=Al@i0, 2=Ah@j0, 3=Al@j0)
    const unsigned short* src = (w & 1) ? Al : Ah;
    const int rowbase = (w < 2) ? i0 : j0;
    int goffs[12];
#pragma unroll
    for (int s = 0; s < 12; ++s) {
        int rt    = 16 * s + (lane >> 2);          // row within tile 0..191
        int chunk = (lane & 3) ^ ((rt >> 1) & 3);  // inverse swizzle on source
        goffs[s]  = (rowbase + rt) * (NN * 2) + kbase + chunk * 16;
    }

    // ---- fragment read offsets (swizzled). Row = 64 B = K=32; MFMA k-half h2
    // reads global chunk g = h2*2 + (lane>>5) at swizzled position.
    int aoff[3][2], boff[3][2];
#pragma unroll
    for (int m = 0; m < 3; ++m) {
        int ra = wr * 96 + m * 32 + (lane & 31);
        int rb = wc * 96 + m * 32 + (lane & 31);
#pragma unroll
        for (int h2 = 0; h2 < 2; ++h2) {
            int g = h2 * 2 + (lane >> 5);
            aoff[m][h2] = ra * 64 + ((g ^ ((ra >> 1) & 3)) * 16);
            boff[m][h2] = rb * 64 + ((g ^ ((rb >> 1) & 3)) * 16);
        }
    }

    f32x16 acc[3][3];
#pragma unroll
    for (int m = 0; m < 3; ++m)
#pragma unroll
        for (int n = 0; n < 3; ++n)
#pragma unroll
            for (int e = 0; e < 16; ++e) acc[m][n][e] = 0.f;

    auto compute = [&](const char* buf) {
#pragma unroll
        for (int h2 = 0; h2 < 2; ++h2) {
            bf16x8 ahf[3], alf[3], bhf[3], blf[3];
#pragma unroll
            for (int m = 0; m < 3; ++m) {
                ahf[m] = *(const bf16x8*)(buf + 0     + aoff[m][h2]);
                alf[m] = *(const bf16x8*)(buf + 12288 + aoff[m][h2]);
                bhf[m] = *(const bf16x8*)(buf + 24576 + boff[m][h2]);
                blf[m] = *(const bf16x8*)(buf + 36864 + boff[m][h2]);
            }
#pragma unroll
            for (int m = 0; m < 3; ++m)
#pragma unroll
                for (int n = 0; n < 3; ++n) {
                    acc[m][n] = __builtin_amdgcn_mfma_f32_32x32x16_bf16(ahf[m], bhf[n], acc[m][n], 0, 0, 0);
                    acc[m][n] = __builtin_amdgcn_mfma_f32_32x32x16_bf16(alf[m], bhf[n], acc[m][n], 0, 0, 0);
                    acc[m][n] = __builtin_amdgcn_mfma_f32_32x32x16_bf16(ahf[m], blf[n], acc[m][n], 0, 0, 0);
                }
        }
    };

    // ---- prologue: stage k-tiles 0,1 into buffers 0,1
#pragma unroll
    for (int s = 0; s < 12; ++s)
        gload_lds16((const char*)src + goffs[s], smem + w * 12288 + s * 1024);
#pragma unroll
    for (int s = 0; s < 12; ++s)
        gload_lds16((const char*)src + goffs[s] + 64, smem + 49152 + w * 12288 + s * 1024);

    // ---- main loop: counted vmcnt(12) retires tile kt (kt+1's 12 in flight)
    for (int kt = 0; kt < NTH - 1; ++kt) {
        asm volatile("s_waitcnt vmcnt(12)" ::: "memory");
        __builtin_amdgcn_s_barrier();
        if (kt + 2 < NTH) {   // stage kt+2 AFTER barrier (its buffer is free)
            char* dst = smem + ((kt + 2) % 3) * 49152 + w * 12288;
            const int kbyte = (kt + 2) * (KS * 2);
#pragma unroll
            for (int s = 0; s < 12; ++s)
                gload_lds16((const char*)src + goffs[s] + kbyte, dst + s * 1024);
        }
        compute(smem + (kt % 3) * 49152);
    }
    asm volatile("s_waitcnt vmcnt(0)" ::: "memory");
    __builtin_amdgcn_s_barrier();
    compute(smem + ((NTH - 1) % 3) * 49152);

    // ---- epilogue: plain stores to this quarter's partial buffer.
    // C/D 32x32: col = lane&31, row = (reg&3) + 8*(reg>>2) + 4*(lane>>5).
    float* dst = Pk + (size_t)kh * NN * NN;
    const int ccol   = lane & 31;
    const int rbase4 = 4 * (lane >> 5);
#pragma unroll
    for (int m = 0; m < 3; ++m)
#pragma unroll
        for (int n = 0; n < 3; ++n) {
            const int gi = i0 + wr * 96 + m * 32 + rbase4;
            const int gj = j0 + wc * 96 + n * 32 + ccol;
#pragma unroll
            for (int r = 0; r < 16; ++r) {
                int row = gi + (r & 3) + 8 * (r >> 2);
                dst[(size_t)row * NN + gj] = acc[m][n][r];
            }
        }
}

// ---------------------------------------------------------------------------
// Conv pass: out[i,j] = A[i,j]*(m1+bb1) + (P0+P1+P2+P3)[i,j]*(m2+bb2) + diag
// 1152 blocks: 8 i-rows (QI tile in LDS) x 256 j (RJ in registers).
// f16 packed math: pk_add + pk_max + v_dot2_f32_f16.
// ---------------------------------------------------------------------------
__global__ __launch_bounds__(256) void gud_conv(
        const float* __restrict__ A,
        const float* __restrict__ Pk,
        const _Float16* __restrict__ QIh,
        const _Float16* __restrict__ RJh,
        const float* __restrict__ b1,
        const float* __restrict__ W2,
        const float* __restrict__ b2,
        float* __restrict__ out) {
    __shared__ uint4 QIs[64];          // 8 rows x 128 B

    const int tid = threadIdx.x;
    const int j   = blockIdx.x * 256 + tid;
    const int i0  = blockIdx.y * 8;

    if (tid < 64) {
        int row = tid >> 3, c = tid & 7;
        QIs[tid] = ((const uint4*)(QIh + (size_t)(i0 + row) * 64))[c];
    }

    uint4 rj4[8];
#pragma unroll
    for (int c = 0; c < 8; ++c)
        rj4[c] = ((const uint4*)(RJh + (size_t)j * 64))[c];
    const unsigned* rw = (const unsigned*)rj4;

    // W2 layers 1,2 concat (feature f -> W2[32+f]) as f16 pairs
    h16x2 w2h[32];
#pragma unroll
    for (int k = 0; k < 32; ++k) {
        h16x2 t; t.x = (_Float16)W2[32 + 2 * k]; t.y = (_Float16)W2[33 + 2 * k];
        w2h[k] = t;
    }
    float c0 = b2[0];
#pragma unroll
    for (int f = 0; f < FDIM; ++f) c0 = fmaf(fmaxf(b1[f], 0.f), W2[f], c0);
    const float bb1 = b2[1], bb2 = b2[2];
    const h16x2 z = {(_Float16)0, (_Float16)0};

    const float* P0 = Pk;
    const float* P1 = Pk + (size_t)NN * NN;
    const float* P2 = Pk + 2 * (size_t)NN * NN;
    const float* P3 = Pk + 3 * (size_t)NN * NN;

    __syncthreads();

#pragma unroll
    for (int ii = 0; ii < 8; ++ii) {
        uint4 q4[8];
#pragma unroll
        for (int c = 0; c < 8; ++c) q4[c] = QIs[ii * 8 + c];
        const unsigned* qw = (const unsigned*)q4;

        float m1 = 0.f, m2 = 0.f;
#pragma unroll
        for (int k = 0; k < 16; ++k) {
            h16x2 h = __builtin_bit_cast(h16x2, qw[k]) + __builtin_bit_cast(h16x2, rw[k]);
            h = __builtin_elementwise_max(h, z);
            m1 = __builtin_amdgcn_fdot2(h, w2h[k], m1, false);
        }
#pragma unroll
        for (int k = 16; k < 32; ++k) {
            h16x2 h = __builtin_bit_cast(h16x2, qw[k]) + __builtin_bit_cast(h16x2, rw[k]);
            h = __builtin_elementwise_max(h, z);
            m2 = __builtin_amdgcn_fdot2(h, w2h[k], m2, false);
        }

        const size_t off = (size_t)(i0 + ii) * NN + j;
        float a2 = (P0[off] + P1[off]) + (P2[off] + P3[off]);
        float v = A[off] * (m1 + bb1) + a2 * (m2 + bb2);
        if (i0 + ii == j) v += c0;
        out[off] = v;
    }
}

// ---------------------------------------------------------------------------
extern "C" void kernel_launch(void* const* d_in, const int* in_sizes, int n_in,
                              void* d_out, int out_size, void* d_ws, size_t ws_size,
                              hipStream_t stream) {
    const float* A  = (const float*)d_in[0];   // [NN,NN] A_norm (symmetric)
    const float* P  = (const float*)d_in[1];   // [NN,32]
    const float* W1 = (const float*)d_in[2];   // [3,32,32]
    const float* b1 = (const float*)d_in[3];   // [3,32]
    const float* W2 = (const float*)d_in[4];   // [3,32,1]
    const float* b2 = (const float*)d_in[5];   // [3,1]
    float* out = (float*)d_out;

    float* Pk = (float*)d_ws;                                    // 4 x NN*NN f32
    unsigned short* Ahh = (unsigned short*)(Pk + 4 * (size_t)NN * NN);  // NN*NN bf16
    unsigned short* All = Ahh + (size_t)NN * NN;                 // NN*NN bf16
    _Float16* QIh = (_Float16*)(All + (size_t)NN * NN);          // NN*64 f16
    _Float16* RJh = QIh + (size_t)NN * 64;                       // NN*64 f16

    gud_split<<<dim3(NN * NN / 1024), 256, 0, stream>>>(A, Ahh, All);
    gud_prep<<<dim3(NN * 64 / 256), 256, 0, stream>>>(P, W1, b1, QIh, RJh);
    gud_gemm<<<dim3((NN / TG) * (NN / TG) * NSPLIT), 256, 0, stream>>>(Ahh, All, Pk);
    gud_conv<<<dim3(NN / 256, NN / 8), 256, 0, stream>>>(A, Pk, QIh, RJh,
                                                         b1, W2, b2, out);
}

// Round 13
// 48.009 us; speedup vs baseline: 1.1691x; 1.1121x over previous
//
#include <hip/hip_runtime.h>
#include <hip/hip_fp16.h>

#define NN 1536      // n_nodes
#define FDIM 32      // p == fts == 32
#define TG 96        // tile (grid 16x16 = 256 blocks = 1/CU, 8 waves each)
#define KS 32        // K-step per half (64 B LDS row)
#define NTH 24       // K-steps per half (768/32)

typedef __attribute__((ext_vector_type(8))) __bf16 bf16x8;
typedef __attribute__((ext_vector_type(4))) float f32x4;
typedef _Float16 h16x2 __attribute__((ext_vector_type(2)));

typedef __attribute__((address_space(3))) unsigned char as3_u8;
typedef __attribute__((address_space(1))) unsigned char as1_u8;

__device__ __forceinline__ void gload_lds16(const void* g, void* l) {
    __builtin_amdgcn_global_load_lds((const as1_u8*)g, (as3_u8*)l, 16, 0, 0);
}

__device__ __forceinline__ unsigned short bf16rne(float f) {
    unsigned u = __float_as_uint(f);
    return (unsigned short)((u + 0x7FFFu + ((u >> 16) & 1u)) >> 16);
}

// ---------------------------------------------------------------------------
// Fused split (A -> bf16 hi/lo) + prep (Q_l = P @ W1[l], f16 QI/RJ).
// Blocks [0, 2304): split.  Blocks [2304, 2688): prep.
// ---------------------------------------------------------------------------
__global__ __launch_bounds__(256) void gud_splitprep(
        const float* __restrict__ A,
        unsigned short* __restrict__ Ah,
        unsigned short* __restrict__ Al,
        const float* __restrict__ P,
        const float* __restrict__ W1,
        const float* __restrict__ b1,
        _Float16* __restrict__ QIh,
        _Float16* __restrict__ RJh) {
    const int b = blockIdx.x;
    if (b < NN * NN / 1024) {
        int gid = b * 256 + threadIdx.x;           // 4 floats per thread
        float4 v = reinterpret_cast<const float4*>(A)[gid];
        ushort4 h, l;
        float x;
        x = v.x; h.x = bf16rne(x); l.x = bf16rne(x - __uint_as_float((unsigned)h.x << 16));
        x = v.y; h.y = bf16rne(x); l.y = bf16rne(x - __uint_as_float((unsigned)h.y << 16));
        x = v.z; h.z = bf16rne(x); l.z = bf16rne(x - __uint_as_float((unsigned)h.z << 16));
        x = v.w; h.w = bf16rne(x); l.w = bf16rne(x - __uint_as_float((unsigned)h.w << 16));
        reinterpret_cast<ushort4*>(Ah)[gid] = h;
        reinterpret_cast<ushort4*>(Al)[gid] = l;
    } else {
        int gid = (b - NN * NN / 1024) * 256 + threadIdx.x;   // 0 .. NN*64-1
        int i  = gid >> 6;
        int lf = gid & 63;
        int l  = (lf >> 5) + 1;   // 1 or 2
        int f  = lf & 31;
        const float* prow = P + i * FDIM;
        const float* wp   = W1 + l * FDIM * FDIM + f;
        float q = 0.f;
#pragma unroll
        for (int c = 0; c < FDIM; ++c) q = fmaf(prow[c], wp[c * FDIM], q);
        QIh[i * 64 + lf] = (_Float16)(q + b1[l * FDIM + f]);
        RJh[i * 64 + lf] = (_Float16)(-q);
    }
}

// ---------------------------------------------------------------------------
// Fully fused GEMM + conv. 512 threads = 8 waves = (kh, wr, wc):
// K split across WAVES (2 waves/SIMD -> m114 overlap, no partial HBM trip).
// Each wave: r3 pipeline (3 bufs, 2-deep prefetch, counted vmcnt(6)) over its
// 768-wide K-half; kh=1 accs exchanged through LDS; kh=0 waves run the f16
// conv epilogue: out = A*(m1+bb1) + A2*(m2+bb2) + diag(c0).
// ---------------------------------------------------------------------------
__global__ __launch_bounds__(512, 1) void gud_fused(
        const unsigned short* __restrict__ Ah,
        const unsigned short* __restrict__ Al,
        const float* __restrict__ A,
        const _Float16* __restrict__ QIh,
        const _Float16* __restrict__ RJh,
        const float* __restrict__ b1,
        const float* __restrict__ W2,
        const float* __restrict__ b2,
        float* __restrict__ out) {
    // 3 buffers x (2 halves x 4 subtiles x 96 rows x 64 B) = 3 x 49152
    __shared__ char smem[3 * 49152];

    const int tid  = threadIdx.x;
    const int lane = tid & 63;
    const int w    = tid >> 6;          // wave 0..7
    const int kh   = w >> 2;            // K-half
    const int sub  = w & 3;             // 0=Ah@i0, 1=Al@i0, 2=Ah@j0, 3=Al@j0
    const int wr   = sub >> 1, wc = sub & 1;

    // XCD-chunked swizzle over the 256-block grid (256 % 8 == 0)
    const int lin = blockIdx.x;
    const int swz = (lin & 7) * 32 + (lin >> 3);
    const int by  = swz >> 4, bx = swz & 15;
    const int i0  = by * TG, j0 = bx * TG;

    // ---- staging: wave w owns subtile (kh, sub) of each buffer
    const unsigned short* src = (sub & 1) ? Al : Ah;
    const int rowbase = (sub < 2) ? i0 : j0;
    const int khbyte  = kh * NN;        // kh * 768 cols * 2 B
    int goffs[6];
#pragma unroll
    for (int s = 0; s < 6; ++s) {
        int rt    = 16 * s + (lane >> 2);          // row within tile 0..95
        int chunk = (lane & 3) ^ ((rt >> 1) & 3);  // inverse swizzle on source
        goffs[s]  = (rowbase + rt) * (NN * 2) + khbyte + chunk * 16;
    }

    // ---- fragment read offsets (within this half's region of a buffer)
    const int hbase = kh * 24576;
    int aoff[3], boff[3];
    const int kb = lane >> 4;
#pragma unroll
    for (int m = 0; m < 3; ++m) {
        int ra  = wr * 48 + m * 16 + (lane & 15);
        aoff[m] = hbase + ra * 64 + ((kb ^ ((ra >> 1) & 3)) * 16);
        int rb  = wc * 48 + m * 16 + (lane & 15);
        boff[m] = hbase + 12288 + rb * 64 + ((kb ^ ((rb >> 1) & 3)) * 16);
    }

    f32x4 acc[3][3];
#pragma unroll
    for (int m = 0; m < 3; ++m)
#pragma unroll
        for (int n = 0; n < 3; ++n) acc[m][n] = (f32x4){0.f, 0.f, 0.f, 0.f};

    auto compute = [&](const char* buf) {
        bf16x8 ahf[3], alf[3], bhf[3], blf[3];
#pragma unroll
        for (int m = 0; m < 3; ++m) {
            ahf[m] = *(const bf16x8*)(buf + aoff[m]);
            alf[m] = *(const bf16x8*)(buf + aoff[m] + 6144);
            bhf[m] = *(const bf16x8*)(buf + boff[m]);
            blf[m] = *(const bf16x8*)(buf + boff[m] + 6144);
        }
#pragma unroll
        for (int m = 0; m < 3; ++m)
#pragma unroll
            for (int n = 0; n < 3; ++n) {
                acc[m][n] = __builtin_amdgcn_mfma_f32_16x16x32_bf16(ahf[m], bhf[n], acc[m][n], 0, 0, 0);
                acc[m][n] = __builtin_amdgcn_mfma_f32_16x16x32_bf16(alf[m], bhf[n], acc[m][n], 0, 0, 0);
                acc[m][n] = __builtin_amdgcn_mfma_f32_16x16x32_bf16(ahf[m], blf[n], acc[m][n], 0, 0, 0);
            }
    };

    // ---- prologue: stage k-tiles 0,1 into buffers 0,1
#pragma unroll
    for (int s = 0; s < 6; ++s)
        gload_lds16((const char*)src + goffs[s], smem + w * 6144 + s * 1024);
#pragma unroll
    for (int s = 0; s < 6; ++s)
        gload_lds16((const char*)src + goffs[s] + 64, smem + 49152 + w * 6144 + s * 1024);

    // ---- main loop: counted vmcnt(6) (per-wave counters) + raw barrier
    for (int kt = 0; kt < NTH - 1; ++kt) {
        asm volatile("s_waitcnt vmcnt(6)" ::: "memory");
        __builtin_amdgcn_s_barrier();
        if (kt + 2 < NTH) {
            char* dst = smem + ((kt + 2) % 3) * 49152 + w * 6144;
            const int kbyte = (kt + 2) * (KS * 2);
#pragma unroll
            for (int s = 0; s < 6; ++s)
                gload_lds16((const char*)src + goffs[s] + kbyte, dst + s * 1024);
        }
        compute(smem + (kt % 3) * 49152);
    }
    asm volatile("s_waitcnt vmcnt(0)" ::: "memory");
    __builtin_amdgcn_s_barrier();
    compute(smem + ((NTH - 1) % 3) * 49152);   // buffer 2; bufs 0,1 now free

    // ---- acc exchange (kh=1 -> LDS buf1) + QI/RJ staging (-> buf0)
    if (kh == 1) {
        char* pbase = smem + 49152 + sub * 9216 + lane * 144;
#pragma unroll
        for (int m = 0; m < 3; ++m)
#pragma unroll
            for (int n = 0; n < 3; ++n)
                *(f32x4*)(pbase + (m * 3 + n) * 16) = acc[m][n];
    }
    if (w < 4) {        // QI: 96 rows x 128 B -> smem[0..12288)
#pragma unroll
        for (int sl = 0; sl < 3; ++sl) {
            int base = (w * 3 + sl) * 64;
            int idx  = base + lane;
            int c    = idx / 96;
            int row  = idx - c * 96;
            gload_lds16(QIh + (size_t)(i0 + row) * 64 + c * 8, smem + base * 16);
        }
    } else {            // RJ -> smem[12288..24576)
#pragma unroll
        for (int sl = 0; sl < 3; ++sl) {
            int base = ((w - 4) * 3 + sl) * 64;
            int idx  = base + lane;
            int c    = idx / 96;
            int row  = idx - c * 96;
            gload_lds16(RJh + (size_t)(j0 + row) * 64 + c * 8, smem + 12288 + base * 16);
        }
    }

    // epilogue geometry + early A loads (kh=0 only; latency hides under sync)
    const int crow = (lane >> 4) * 4;
    const int ccol = lane & 15;
    int il[3], jl[3];
#pragma unroll
    for (int m = 0; m < 3; ++m) il[m] = wr * 48 + m * 16 + crow;
#pragma unroll
    for (int n = 0; n < 3; ++n) jl[n] = wc * 48 + n * 16 + ccol;

    float av[3][3][4];
    if (kh == 0) {
#pragma unroll
        for (int m = 0; m < 3; ++m)
#pragma unroll
            for (int n = 0; n < 3; ++n)
#pragma unroll
                for (int r = 0; r < 4; ++r)
                    av[m][n][r] = A[(size_t)(i0 + il[m] + r) * NN + j0 + jl[n]];
    }

    __syncthreads();    // drains vmcnt (QI/RJ, A) + lgkm (acc ds_writes)

    if (kh == 1) return;

    // ---- add partner half's accumulators
    {
        const char* pbase = smem + 49152 + sub * 9216 + lane * 144;
#pragma unroll
        for (int m = 0; m < 3; ++m)
#pragma unroll
            for (int n = 0; n < 3; ++n)
                acc[m][n] += *(const f32x4*)(pbase + (m * 3 + n) * 16);
    }

    // ---- conv epilogue (f16 dot2, two-pass; r7-verified)
    const char* QIl = smem;
    const char* RJl = smem + 12288;

    float c0 = b2[0];
#pragma unroll
    for (int f = 0; f < FDIM; ++f) c0 = fmaf(fmaxf(b1[f], 0.f), W2[f], c0);
    const float bb1 = b2[1], bb2 = b2[2];

    h16x2 w2h[32];
#pragma unroll
    for (int k = 0; k < 32; ++k) {
        h16x2 t; t.x = (_Float16)W2[32 + 2 * k]; t.y = (_Float16)W2[33 + 2 * k];
        w2h[k] = t;
    }

    float mm[3][3][4];
    // pass 1: chunks 0..3 (features 0..31, layer 1) -> m1, fold into av
#pragma unroll
    for (int m = 0; m < 3; ++m)
#pragma unroll
        for (int n = 0; n < 3; ++n)
#pragma unroll
            for (int r = 0; r < 4; ++r) mm[m][n][r] = 0.f;
#pragma unroll
    for (int c = 0; c < 4; ++c) {
        uint4 rv[3];
#pragma unroll
        for (int n = 0; n < 3; ++n)
            rv[n] = *(const uint4*)(RJl + (c * 96 + jl[n]) * 16);
        uint4 qv[3][4];
#pragma unroll
        for (int m = 0; m < 3; ++m)
#pragma unroll
            for (int r = 0; r < 4; ++r)
                qv[m][r] = *(const uint4*)(QIl + (c * 96 + il[m] + r) * 16);
#pragma unroll
        for (int m = 0; m < 3; ++m)
#pragma unroll
            for (int n = 0; n < 3; ++n) {
                const unsigned* ru = (const unsigned*)&rv[n];
#pragma unroll
                for (int r = 0; r < 4; ++r) {
                    const unsigned* qu = (const unsigned*)&qv[m][r];
                    float acc_f = mm[m][n][r];
#pragma unroll
                    for (int e = 0; e < 4; ++e) {
                        h16x2 q = __builtin_bit_cast(h16x2, qu[e]);
                        h16x2 j = __builtin_bit_cast(h16x2, ru[e]);
                        h16x2 h = q + j;
                        h16x2 z = {(_Float16)0, (_Float16)0};
                        h = __builtin_elementwise_max(h, z);
                        acc_f = __builtin_amdgcn_fdot2(h, w2h[c * 4 + e], acc_f, false);
                    }
                    mm[m][n][r] = acc_f;
                }
            }
    }
#pragma unroll
    for (int m = 0; m < 3; ++m)
#pragma unroll
        for (int n = 0; n < 3; ++n)
#pragma unroll
            for (int r = 0; r < 4; ++r)
                av[m][n][r] *= (mm[m][n][r] + bb1);

    // pass 2: chunks 4..7 (features 32..63, layer 2) -> m2
#pragma unroll
    for (int m = 0; m < 3; ++m)
#pragma unroll
        for (int n = 0; n < 3; ++n)
#pragma unroll
            for (int r = 0; r < 4; ++r) mm[m][n][r] = 0.f;
#pragma unroll
    for (int c = 4; c < 8; ++c) {
        uint4 rv[3];
#pragma unroll
        for (int n = 0; n < 3; ++n)
            rv[n] = *(const uint4*)(RJl + (c * 96 + jl[n]) * 16);
        uint4 qv[3][4];
#pragma unroll
        for (int m = 0; m < 3; ++m)
#pragma unroll
            for (int r = 0; r < 4; ++r)
                qv[m][r] = *(const uint4*)(QIl + (c * 96 + il[m] + r) * 16);
#pragma unroll
        for (int m = 0; m < 3; ++m)
#pragma unroll
            for (int n = 0; n < 3; ++n) {
                const unsigned* ru = (const unsigned*)&rv[n];
#pragma unroll
                for (int r = 0; r < 4; ++r) {
                    const unsigned* qu = (const unsigned*)&qv[m][r];
                    float acc_f = mm[m][n][r];
#pragma unroll
                    for (int e = 0; e < 4; ++e) {
                        h16x2 q = __builtin_bit_cast(h16x2, qu[e]);
                        h16x2 j = __builtin_bit_cast(h16x2, ru[e]);
                        h16x2 h = q + j;
                        h16x2 z = {(_Float16)0, (_Float16)0};
                        h = __builtin_elementwise_max(h, z);
                        acc_f = __builtin_amdgcn_fdot2(h, w2h[c * 4 + e], acc_f, false);
                    }
                    mm[m][n][r] = acc_f;
                }
            }
    }

    // final: out = A*(m1+bb1) + A2*(m2+bb2) + diag(c0)
#pragma unroll
    for (int m = 0; m < 3; ++m)
#pragma unroll
        for (int n = 0; n < 3; ++n)
#pragma unroll
            for (int r = 0; r < 4; ++r) {
                float v = av[m][n][r] + acc[m][n][r] * (mm[m][n][r] + bb2);
                int gi = i0 + il[m] + r;
                int gj = j0 + jl[n];
                if (gi == gj) v += c0;
                out[(size_t)gi * NN + gj] = v;
            }
}

// ---------------------------------------------------------------------------
extern "C" void kernel_launch(void* const* d_in, const int* in_sizes, int n_in,
                              void* d_out, int out_size, void* d_ws, size_t ws_size,
                              hipStream_t stream) {
    const float* A  = (const float*)d_in[0];   // [NN,NN] A_norm (symmetric)
    const float* P  = (const float*)d_in[1];   // [NN,32]
    const float* W1 = (const float*)d_in[2];   // [3,32,32]
    const float* b1 = (const float*)d_in[3];   // [3,32]
    const float* W2 = (const float*)d_in[4];   // [3,32,1]
    const float* b2 = (const float*)d_in[5];   // [3,1]
    float* out = (float*)d_out;

    unsigned short* Ahh = (unsigned short*)d_ws;                 // NN*NN bf16
    unsigned short* All = Ahh + (size_t)NN * NN;                 // NN*NN bf16
    _Float16* QIh = (_Float16*)(All + (size_t)NN * NN);          // NN*64 f16
    _Float16* RJh = QIh + (size_t)NN * 64;                       // NN*64 f16

    gud_splitprep<<<dim3(NN * NN / 1024 + NN * 64 / 256), 256, 0, stream>>>(
        A, Ahh, All, P, W1, b1, QIh, RJh);
    gud_fused<<<dim3((NN / TG) * (NN / TG)), 512, 0, stream>>>(
        Ahh, All, A, QIh, RJh, b1, W2, b2, out);
}